// Round 13
// baseline (175.178 us; speedup 1.0000x reference)
//
#include <hip/hip_runtime.h>
#include <math.h>

#define NUM_GRAPHS 512
#define D 128
#define NEG 0.01f
#define BN 128  // nodes per block in MFMA MLP kernel
#define NS 4    // pool row-slices per (graph, tensor)

typedef __attribute__((ext_vector_type(8))) short  bf16x8;  // MFMA A/B frag
typedef __attribute__((ext_vector_type(4))) float  f32x4;   // MFMA C/D frag
typedef __attribute__((ext_vector_type(4))) int    i32x4;

__device__ __forceinline__ unsigned short f2bf(float f) {
    unsigned u = __float_as_uint(f);
    u += 0x7fffu + ((u >> 16) & 1u);   // RNE
    return (unsigned short)(u >> 16);
}

// f32x8 -> 16B of bf16 via packed cvt
__device__ __forceinline__ bf16x8 cvt8(float4 a, float4 b) {
    unsigned w0, w1, w2, w3;
    asm("v_cvt_pk_bf16_f32 %0, %1, %2" : "=v"(w0) : "v"(a.x), "v"(a.y));
    asm("v_cvt_pk_bf16_f32 %0, %1, %2" : "=v"(w1) : "v"(a.z), "v"(a.w));
    asm("v_cvt_pk_bf16_f32 %0, %1, %2" : "=v"(w2) : "v"(b.x), "v"(b.y));
    asm("v_cvt_pk_bf16_f32 %0, %1, %2" : "=v"(w3) : "v"(b.z), "v"(b.w));
    i32x4 v; v[0] = (int)w0; v[1] = (int)w1; v[2] = (int)w2; v[3] = (int)w3;
    return __builtin_bit_cast(bf16x8, v);
}

// swizzled ushort index in the 128-row two-tile LDS image
__device__ __forceinline__ int swz128(int row, int k) {
    return (row >> 6) * 16384 + (row & 63) * 256 + (k ^ ((row & 7) << 3));
}

// raw barrier that does NOT drain vmcnt (keeps global prefetch in flight);
// lgkmcnt(0) publishes LDS writes / retires LDS reads.
#define LDS_BARRIER()                                                        \
    do {                                                                     \
        asm volatile("s_waitcnt lgkmcnt(0)" ::: "memory");                   \
        __builtin_amdgcn_s_barrier();                                        \
        asm volatile("" ::: "memory");                                       \
    } while (0)

#define FMAX4(a, b)                                                          \
    do {                                                                     \
        (a).x = fmaxf((a).x, (b).x); (a).y = fmaxf((a).y, (b).y);            \
        (a).z = fmaxf((a).z, (b).z); (a).w = fmaxf((a).w, (b).w);            \
    } while (0)
#define FADD4(a, b)                                                          \
    do {                                                                     \
        (a).x += (b).x; (a).y += (b).y; (a).z += (b).z; (a).w += (b).w;      \
    } while (0)

// ---------------------------------------------------------------------------
// Kernel 0: segment bounds. seg[g] = lower_bound(batch, g), g in [0, 512].
// ---------------------------------------------------------------------------
__global__ __launch_bounds__(256) void bounds_kernel(
    const int* __restrict__ batch, int N, int* __restrict__ seg)
{
    const int g = blockIdx.x * 256 + threadIdx.x;
    if (g <= NUM_GRAPHS) {
        int lo = 0, hi = N;
        while (lo < hi) { int m = (lo + hi) >> 1; if (batch[m] < g) lo = m + 1; else hi = m; }
        seg[g] = lo;
    }
}

// ---------------------------------------------------------------------------
// Kernel 1: sliced per-graph segment max+sum partials (pure reduction).
// grid=(512, 2, NS); 4 independent acc streams for MLP.
// pp[((g*2+t)*NS+s)*256 + {0..127: max, 128..255: sum}]
// ---------------------------------------------------------------------------
__global__ __launch_bounds__(256) void pool_kernel(
    const float* __restrict__ h_topo, const float* __restrict__ h_geom,
    const int* __restrict__ seg, int N, float* __restrict__ pp)
{
    const int g = blockIdx.x, t = blockIdx.y, s = blockIdx.z;
    const float* __restrict__ h = t ? h_geom : h_topo;

    const int start = seg[g], end = seg[g + 1];
    const int len = end - start;
    const int r0  = start + (int)(((long long)len * s) / NS);
    const int r1  = start + (int)(((long long)len * (s + 1)) / NS);

    const int c = threadIdx.x & 31;   // float4 column
    const int r = threadIdx.x >> 5;   // 0..7 row phase

    float4 mxA = make_float4(-INFINITY, -INFINITY, -INFINITY, -INFINITY);
    float4 mxB = mxA, mxC = mxA, mxD = mxA;
    float4 smA = make_float4(0.f, 0.f, 0.f, 0.f);
    float4 smB = smA, smC = smA, smD = smA;

    int row = r0 + r;
    for (; row + 24 < r1; row += 32) {
        float4 v0 = *(const float4*)(h + (size_t)row * D + c * 4);
        float4 v1 = *(const float4*)(h + (size_t)(row + 8)  * D + c * 4);
        float4 v2 = *(const float4*)(h + (size_t)(row + 16) * D + c * 4);
        float4 v3 = *(const float4*)(h + (size_t)(row + 24) * D + c * 4);
        FMAX4(mxA, v0); FADD4(smA, v0);
        FMAX4(mxB, v1); FADD4(smB, v1);
        FMAX4(mxC, v2); FADD4(smC, v2);
        FMAX4(mxD, v3); FADD4(smD, v3);
    }
    for (; row < r1; row += 8) {
        float4 v = *(const float4*)(h + (size_t)row * D + c * 4);
        FMAX4(mxA, v); FADD4(smA, v);
    }
    FMAX4(mxA, mxB); FMAX4(mxC, mxD); FMAX4(mxA, mxC);
    FADD4(smA, smB); FADD4(smC, smD); FADD4(smA, smC);

    __shared__ float4 smx[256], ssm[256];
    smx[threadIdx.x] = mxA; ssm[threadIdx.x] = smA;
    __syncthreads();
    #pragma unroll
    for (int st = 4; st > 0; st >>= 1) {
        if (r < st) {
            float4 a = smx[threadIdx.x + st * 32];
            float4 b = ssm[threadIdx.x + st * 32];
            float4 m0 = smx[threadIdx.x];
            float4 s0 = ssm[threadIdx.x];
            FMAX4(m0, a); FADD4(s0, b);
            smx[threadIdx.x] = m0; ssm[threadIdx.x] = s0;
        }
        __syncthreads();
    }
    if (r == 0) {
        float* dst = pp + ((size_t)(g * 2 + t) * NS + s) * 256;
        *(float4*)(dst + c * 4)       = smx[threadIdx.x];   // raw max partial
        *(float4*)(dst + 128 + c * 4) = ssm[threadIdx.x];   // raw sum partial
    }
}

// ---------------------------------------------------------------------------
// Kernel 2: finalize partials + per-graph bias
// P[g][j] = b1[j] + pooled[g] . W1[pooled rows][j]
// ---------------------------------------------------------------------------
__global__ __launch_bounds__(256) void pmat_kernel(
    const float* __restrict__ pp, const int* __restrict__ seg,
    const float* __restrict__ W1, const float* __restrict__ b1,
    float* __restrict__ P)
{
    const int g = blockIdx.x;
    const int j = threadIdx.x;

    const int start = seg[g], end = seg[g + 1];
    const float inv   = 1.0f / fmaxf((float)(end - start), 1.0f);
    const bool  empty = (end <= start);

    __shared__ float pl[512];
    #pragma unroll
    for (int e0 = 0; e0 < 2; ++e0) {
        const int e = j + e0 * 256;
        const int t = e >> 8, i = e & 255;
        const float* q = pp + (size_t)(g * 2 + t) * NS * 256 + i;
        float v;
        if (i < 128)
            v = fmaxf(fmaxf(q[0], q[256]), fmaxf(q[512], q[768]));
        else
            v = (q[0] + q[256] + q[512] + q[768]) * inv;
        pl[e] = empty ? 0.f : v;
    }
    __syncthreads();

    float acc = b1[j];
    #pragma unroll 8
    for (int k = 0; k < 256; ++k)          // t_max,t_mean -> W1 rows 128..383
        acc += pl[k] * W1[(size_t)(128 + k) * 256 + j];
    #pragma unroll 8
    for (int k = 0; k < 256; ++k)          // g_max,g_mean -> W1 rows 512..767
        acc += pl[256 + k] * W1[(size_t)(512 + k) * 256 + j];

    P[(size_t)g * 256 + j] = acc;
}

// ---------------------------------------------------------------------------
// Kernel 3: weight pre-convert to transposed bf16.
// ---------------------------------------------------------------------------
__global__ __launch_bounds__(256) void wconv_kernel(
    const float* __restrict__ W1, const float* __restrict__ W2,
    unsigned short* __restrict__ W1bT, unsigned short* __restrict__ W2bT)
{
    const int idx = blockIdx.x * 256 + threadIdx.x;
    if (idx < 256 * 256) {
        const int n = idx >> 8, k = idx & 255;
        const int kk = (k < 128) ? k : (k + 256);
        W1bT[idx] = f2bf(W1[(size_t)kk * 256 + n]);
    } else {
        const int j = idx - 256 * 256;
        if (j < 128 * 256) {
            const int n = j >> 8, k = j & 255;
            W2bT[j] = f2bf(W2[(size_t)k * 128 + n]);
        }
    }
}

// ---------------------------------------------------------------------------
// Kernel 4: fused MFMA MLP. 128 nodes/block, 8 waves (512 thr).
// GEMM2 re-tiled for FULL-LINE writes: wave w owns j-pair jp=w&3 (cols
// [32jp,32jp+32) = one 128B line) x node-group ng=w>>2 (64 nodes). Every
// 128B out-line is produced entirely by one wave -> NT float4 stores write
// exact full lines (no RMW amplification). H LDS reads halve (frag reuse).
// Blocks process tiles in REVERSE so mlp starts on the X-tail pool touched
// last (L3-fresh).
// ---------------------------------------------------------------------------
__global__ __launch_bounds__(512, 4) void mlp_mfma(
    const float* __restrict__ h_topo, const float* __restrict__ h_geom,
    const int* __restrict__ batch, const float* __restrict__ P,
    const unsigned short* __restrict__ W1bT, const unsigned short* __restrict__ W2bT,
    const float* __restrict__ b2, float* __restrict__ out, int N)
{
    __shared__ unsigned short xs[128 * 256];   // 64 KB, X then H (swz128 layout)
    __shared__ int gid[128];

    const int tid  = threadIdx.x;
    const int wave = tid >> 6, lane = tid & 63;
    const int base = (gridDim.x - 1 - blockIdx.x) * BN;   // reverse order

    // ---- stage X: row = tid>>2 (0..127), kq = tid&3 (64-dim chunk) ----
    {
        const int row  = tid >> 2, kq = tid & 3;
        const int node = min(base + row, N - 1);
        const float* src = (kq < 2) ? h_topo + (size_t)node * D + kq * 64
                                    : h_geom + (size_t)node * D + (kq - 2) * 64;
        #pragma unroll
        for (int i = 0; i < 8; ++i) {
            float4 a = ((const float4*)src)[2 * i];
            float4 b = ((const float4*)src)[2 * i + 1];
            *(bf16x8*)&xs[swz128(row, kq * 64 + i * 8)] = cvt8(a, b);
        }
    }
    if (tid < 128) gid[tid] = batch[min(base + tid, N - 1)];

    const int g0 = batch[base];
    const int g1 = batch[min(base + 127, N - 1)];
    const bool uni = (g0 == g1);

    const int lhi = lane >> 4;   // 0..3
    const int llo = lane & 15;   // 0..15

    const unsigned short* w1p = W1bT + (size_t)(wave * 32 + llo) * 256 + lhi * 8;

    float pf[2];
    if (uni) {
        #pragma unroll
        for (int ct = 0; ct < 2; ++ct)
            pf[ct] = P[(size_t)g0 * 256 + wave * 32 + ct * 16 + llo];
    }

    // ---- preload GEMM1 ks=0,1 weight frags (stay pending across barrier) ----
    bf16x8 bfr[2][2];
    #pragma unroll
    for (int ct = 0; ct < 2; ++ct) {
        bfr[0][ct] = *(const bf16x8*)(w1p + (size_t)ct * 16 * 256);
        bfr[1][ct] = *(const bf16x8*)(w1p + (size_t)ct * 16 * 256 + 32);
    }

    LDS_BARRIER();   // X image published (lgkm only; weight vm loads in flight)

    // ---- GEMM1: 8 row-tiles x 2 col-tiles, dist-2 W prefetch ----
    f32x4 acc[8][2];
    #pragma unroll
    for (int rt = 0; rt < 8; ++rt)
        #pragma unroll
        for (int ct = 0; ct < 2; ++ct) {
            const float p = uni ? pf[ct] : 0.f;
            acc[rt][ct] = (f32x4){p, p, p, p};
        }

    #pragma unroll
    for (int ks = 0; ks < 8; ++ks) {
        const int kb = ks * 32 + lhi * 8;
        bf16x8 afr[8];
        #pragma unroll
        for (int rt = 0; rt < 8; ++rt)
            afr[rt] = *(const bf16x8*)&xs[swz128(rt * 16 + llo, kb)];
        __builtin_amdgcn_s_setprio(1);
        #pragma unroll
        for (int rt = 0; rt < 8; ++rt)
            #pragma unroll
            for (int ct = 0; ct < 2; ++ct)
                acc[rt][ct] = __builtin_amdgcn_mfma_f32_16x16x32_bf16(
                    afr[rt], bfr[ks & 1][ct], acc[rt][ct], 0, 0, 0);
        __builtin_amdgcn_s_setprio(0);
        if (ks < 6) {
            const int kbn = (ks + 2) * 32;
            #pragma unroll
            for (int ct = 0; ct < 2; ++ct)
                bfr[ks & 1][ct] = *(const bf16x8*)(w1p + (size_t)ct * 16 * 256 + kbn);
        }
    }

    // ---- GEMM2 tiling: jp = wave&3 (j-cols [32jp,32jp+32)), ng = wave>>2 ----
    const int jp = wave & 3, ng = wave >> 2;
    const unsigned short* w2pA = W2bT + (size_t)((2 * jp)     * 16 + llo) * 256 + lhi * 8;
    const unsigned short* w2pB = W2bT + (size_t)((2 * jp + 1) * 16 + llo) * 256 + lhi * 8;

    // issue GEMM2 ks=0,1 W2 frags (in flight across barriers)
    bf16x8 bfr2[2][2];
    bfr2[0][0] = *(const bf16x8*)(w2pA);
    bfr2[0][1] = *(const bf16x8*)(w2pB);
    bfr2[1][0] = *(const bf16x8*)(w2pA + 32);
    bfr2[1][1] = *(const bf16x8*)(w2pB + 32);

    LDS_BARRIER();   // all waves done reading X (lgkm only)

    // ---- epilogue 1: (+P if boundary tile), LeakyReLU, H -> xs (bf16) ----
    #pragma unroll
    for (int rt = 0; rt < 8; ++rt) {
        #pragma unroll
        for (int ct = 0; ct < 2; ++ct) {
            const int col = wave * 32 + ct * 16 + llo;
            #pragma unroll
            for (int q = 0; q < 4; ++q) {
                const int row = rt * 16 + lhi * 4 + q;
                float v = acc[rt][ct][q];
                if (!uni) v += P[(size_t)gid[row] * 256 + col];
                v = fmaxf(v, NEG * v);   // LeakyReLU
                xs[swz128(row, col)] = f2bf(v);
            }
        }
    }

    LDS_BARRIER();   // H published

    // ---- GEMM2 (transposed): D[j][node], wave covers 64 nodes x 32 j-cols ----
    f32x4 acc2[4][2];
    {
        const float4 bbA = *(const float4*)(b2 + (2 * jp)     * 16 + lhi * 4);
        const float4 bbB = *(const float4*)(b2 + (2 * jp + 1) * 16 + lhi * 4);
        #pragma unroll
        for (int nt = 0; nt < 4; ++nt) {
            acc2[nt][0] = (f32x4){bbA.x, bbA.y, bbA.z, bbA.w};
            acc2[nt][1] = (f32x4){bbB.x, bbB.y, bbB.z, bbB.w};
        }
    }
    #pragma unroll
    for (int ks = 0; ks < 8; ++ks) {
        const int kb = ks * 32 + lhi * 8;
        bf16x8 hfr[4];
        #pragma unroll
        for (int nt = 0; nt < 4; ++nt)
            hfr[nt] = *(const bf16x8*)&xs[swz128((ng * 4 + nt) * 16 + llo, kb)];
        __builtin_amdgcn_s_setprio(1);
        #pragma unroll
        for (int nt = 0; nt < 4; ++nt) {
            acc2[nt][0] = __builtin_amdgcn_mfma_f32_16x16x32_bf16(
                bfr2[ks & 1][0], hfr[nt], acc2[nt][0], 0, 0, 0);
            acc2[nt][1] = __builtin_amdgcn_mfma_f32_16x16x32_bf16(
                bfr2[ks & 1][1], hfr[nt], acc2[nt][1], 0, 0, 0);
        }
        __builtin_amdgcn_s_setprio(0);
        if (ks < 6) {
            bfr2[ks & 1][0] = *(const bf16x8*)(w2pA + (ks + 2) * 32);
            bfr2[ks & 1][1] = *(const bf16x8*)(w2pB + (ks + 2) * 32);
        }
    }

    // ---- store out: full 128B lines per wave, non-temporal float4 ----
    #pragma unroll
    for (int nt = 0; nt < 4; ++nt) {
        const int node = base + (ng * 4 + nt) * 16 + llo;
        if (node < N) {
            float* op = out + (size_t)node * 128 + jp * 32 + lhi * 4;
            __builtin_nontemporal_store(acc2[nt][0], (f32x4*)op);
            __builtin_nontemporal_store(acc2[nt][1], (f32x4*)(op + 16));
        }
    }
}

// ---------------------------------------------------------------------------
extern "C" void kernel_launch(void* const* d_in, const int* in_sizes, int n_in,
                              void* d_out, int out_size, void* d_ws, size_t ws_size,
                              hipStream_t stream)
{
    const float* h_topo = (const float*)d_in[0];
    const float* h_geom = (const float*)d_in[1];
    const int*   batch  = (const int*)  d_in[2];
    const float* W1     = (const float*)d_in[3];
    const float* b1     = (const float*)d_in[4];
    const float* W2     = (const float*)d_in[5];
    const float* b2     = (const float*)d_in[6];
    float* out = (float*)d_out;

    const int N = in_sizes[0] / D;   // 200000

    // ws layout: pp (4MB) | P (512KB) | W1bT | W2bT | seg (~2KB)
    float*          pp   = (float*)d_ws;
    float*          P    = pp + (size_t)NUM_GRAPHS * 2 * NS * 256;
    unsigned short* W1bT = (unsigned short*)(P + (size_t)NUM_GRAPHS * 256);
    unsigned short* W2bT = W1bT + 256 * 256;
    int*            seg  = (int*)(W2bT + 128 * 256);

    bounds_kernel<<<3, 256, 0, stream>>>(batch, N, seg);
    wconv_kernel<<<(256 * 256 + 128 * 256) / 256, 256, 0, stream>>>(W1, W2, W1bT, W2bT);
    pool_kernel<<<dim3(NUM_GRAPHS, 2, NS), 256, 0, stream>>>(h_topo, h_geom, seg, N, pp);
    pmat_kernel<<<NUM_GRAPHS, 256, 0, stream>>>(pp, seg, W1, b1, P);

    const int nblocks = (N + BN - 1) / BN;   // 1563
    mlp_mfma<<<nblocks, 512, 0, stream>>>(h_topo, h_geom, batch, P,
                                          W1bT, W2bT, b2, out, N);
}